// Round 1
// baseline (649.222 us; speedup 1.0000x reference)
//
#include <hip/hip_runtime.h>
#include <hip/hip_bf16.h>
#include <math.h>

constexpr int NB = 256;    // batch
constexpr int NS = 512;    // source positions
constexpr int ND = 1024;   // hidden
constexpr int NV = 50257;  // vocab

// ---------------------------------------------------------------------------
// Tiled f32 GEMM: C[M,N] = act(A[M,K] @ Bm[K,N] + bias[N])
// BM=64, BN=64, BK=16, 256 threads, 4x4 accumulators per thread.
// ---------------------------------------------------------------------------
template<bool TANH_ACT>
__global__ __launch_bounds__(256)
void gemm_bias(const float* __restrict__ A, const float* __restrict__ Bm,
               const float* __restrict__ bias, float* __restrict__ C,
               int M, int N, int K) {
  constexpr int BM = 64, BN = 64, BK = 16, PAD = 4;
  __shared__ float As[BK][BM + PAD];   // k-major so inner loop reads are contiguous
  __shared__ float Bs[BK][BN + PAD];
  const int tid = threadIdx.x;
  const int tx = tid & 15;   // output col group
  const int ty = tid >> 4;   // output row group
  const int row0 = blockIdx.y * BM;
  const int col0 = blockIdx.x * BN;

  float acc[4][4] = {};

  for (int k0 = 0; k0 < K; k0 += BK) {
    // A tile 64x16 -> As[k][m]
#pragma unroll
    for (int l = 0; l < 4; ++l) {
      int e = tid + l * 256;
      int r = e >> 4;        // m within tile
      int c = e & 15;        // k within tile
      As[c][r] = A[(row0 + r) * K + k0 + c];
    }
    // B tile 16x64 -> Bs[k][n]
#pragma unroll
    for (int l = 0; l < 4; ++l) {
      int e = tid + l * 256;
      int r = e >> 6;        // k within tile
      int c = e & 63;        // n within tile
      int col = col0 + c;
      Bs[r][c] = (col < N) ? Bm[(k0 + r) * N + col] : 0.0f;
    }
    __syncthreads();
#pragma unroll
    for (int k = 0; k < BK; ++k) {
      float a[4], b[4];
#pragma unroll
      for (int i = 0; i < 4; ++i) a[i] = As[k][ty * 4 + i];
#pragma unroll
      for (int j = 0; j < 4; ++j) b[j] = Bs[k][tx * 4 + j];
#pragma unroll
      for (int i = 0; i < 4; ++i)
#pragma unroll
        for (int j = 0; j < 4; ++j)
          acc[i][j] += a[i] * b[j];
    }
    __syncthreads();
  }

#pragma unroll
  for (int i = 0; i < 4; ++i) {
    int row = row0 + ty * 4 + i;
#pragma unroll
    for (int j = 0; j < 4; ++j) {
      int col = col0 + tx * 4 + j;
      if (col < N) {
        float v = acc[i][j] + bias[col];
        if (TANH_ACT) v = tanhf(v);
        C[row * N + col] = v;
      }
    }
  }
}

// ---------------------------------------------------------------------------
// mix = softmax2(h @ W2 + b2), one block per row
// ---------------------------------------------------------------------------
__global__ __launch_bounds__(256)
void gate_mix(const float* __restrict__ h, const float* __restrict__ W2,
              const float* __restrict__ b2, float* __restrict__ mix) {
  const int row = blockIdx.x;
  const int tid = threadIdx.x;
  float g0 = 0.f, g1 = 0.f;
  for (int j = tid; j < ND; j += 256) {
    float hv = h[row * ND + j];
    g0 += hv * W2[j * 2 + 0];
    g1 += hv * W2[j * 2 + 1];
  }
  for (int o = 32; o > 0; o >>= 1) {
    g0 += __shfl_down(g0, o, 64);
    g1 += __shfl_down(g1, o, 64);
  }
  __shared__ float l0[4], l1[4];
  int wid = tid >> 6, lane = tid & 63;
  if (lane == 0) { l0[wid] = g0; l1[wid] = g1; }
  __syncthreads();
  if (tid == 0) {
    float a = l0[0] + l0[1] + l0[2] + l0[3] + b2[0];
    float c = l1[0] + l1[1] + l1[2] + l1[3] + b2[1];
    float m = fmaxf(a, c);
    float e0 = expf(a - m), e1 = expf(c - m);
    float inv = 1.f / (e0 + e1);
    mix[row * 2 + 0] = e0 * inv;
    mix[row * 2 + 1] = e1 * inv;
  }
}

// ---------------------------------------------------------------------------
// alphas = softmax(scores) rowwise, one block (256 thr) per row, S=512
// ---------------------------------------------------------------------------
__global__ __launch_bounds__(256)
void softmax_scores(const float* __restrict__ scores, float* __restrict__ alphas) {
  const int row = blockIdx.x;
  const int tid = threadIdx.x;
  float v0 = scores[row * NS + tid];
  float v1 = scores[row * NS + tid + 256];
  float m = fmaxf(v0, v1);
  for (int o = 32; o > 0; o >>= 1) m = fmaxf(m, __shfl_down(m, o, 64));
  __shared__ float lm[4], ls[4];
  int wid = tid >> 6, lane = tid & 63;
  if (lane == 0) lm[wid] = m;
  __syncthreads();
  float mAll = fmaxf(fmaxf(lm[0], lm[1]), fmaxf(lm[2], lm[3]));
  float e0 = expf(v0 - mAll), e1 = expf(v1 - mAll);
  float s = e0 + e1;
  for (int o = 32; o > 0; o >>= 1) s += __shfl_down(s, o, 64);
  if (lane == 0) ls[wid] = s;
  __syncthreads();
  float inv = 1.f / (ls[0] + ls[1] + ls[2] + ls[3]);
  alphas[row * NS + tid] = e0 * inv;
  alphas[row * NS + tid + 256] = e1 * inv;
}

// ---------------------------------------------------------------------------
// Per-row online max/sum over V logits, one block per row.
// ---------------------------------------------------------------------------
__global__ __launch_bounds__(256)
void row_max_sum(const float* __restrict__ logits, float* __restrict__ stats) {
  const int row = blockIdx.x;
  const int tid = threadIdx.x;
  float m = -INFINITY, s = 0.f;
  for (int c = tid; c < NV; c += 256) {
    float x = logits[row * NV + c];
    float mn = fmaxf(m, x);
    s = s * expf(m - mn) + expf(x - mn);
    m = mn;
  }
  for (int o = 32; o > 0; o >>= 1) {
    float m2 = __shfl_down(m, o, 64);
    float s2 = __shfl_down(s, o, 64);
    float mn = fmaxf(m, m2);
    s = s * expf(m - mn) + s2 * expf(m2 - mn);
    m = mn;
  }
  __shared__ float lm[4], ls[4];
  int wid = tid >> 6, lane = tid & 63;
  if (lane == 0) { lm[wid] = m; ls[wid] = s; }
  __syncthreads();
  if (tid == 0) {
    float M = lm[0], Sv = ls[0];
    for (int w = 1; w < 4; ++w) {
      float mn = fmaxf(M, lm[w]);
      Sv = Sv * expf(M - mn) + ls[w] * expf(lm[w] - mn);
      M = mn;
    }
    stats[row * 2 + 0] = M;
    stats[row * 2 + 1] = Sv;
  }
}

// ---------------------------------------------------------------------------
// out = exp(logit - m)/s * mix0   (in-place on d_out)
// ---------------------------------------------------------------------------
__global__ __launch_bounds__(256)
void finalize_gen(float* __restrict__ out, const float* __restrict__ stats,
                  const float* __restrict__ mix) {
  const int row = blockIdx.y;
  const int col = blockIdx.x * 256 + threadIdx.x;
  if (col < NV) {
    float m = stats[row * 2 + 0], s = stats[row * 2 + 1];
    float g = mix[row * 2 + 0];
    float x = out[row * NV + col];
    out[row * NV + col] = expf(x - m) * (g / s);
  }
}

// ---------------------------------------------------------------------------
// out[row, ctx_ids[row,s]] += alphas[row,s] * mix1[row]
// ---------------------------------------------------------------------------
__global__ __launch_bounds__(512)
void scatter_copy(float* __restrict__ out, const float* __restrict__ alphas,
                  const int* __restrict__ ids, const float* __restrict__ mix) {
  const int row = blockIdx.x;
  const int t = threadIdx.x;
  float a = alphas[row * NS + t] * mix[row * 2 + 1];
  atomicAdd(&out[row * NV + ids[row * NS + t]], a);
}

extern "C" void kernel_launch(void* const* d_in, const int* in_sizes, int n_in,
                              void* d_out, int out_size, void* d_ws, size_t ws_size,
                              hipStream_t stream) {
  const float* x      = (const float*)d_in[0];
  const float* scores = (const float*)d_in[1];
  const int*   ctx    = (const int*)d_in[2];
  const float* Wg     = (const float*)d_in[3];
  const float* bg     = (const float*)d_in[4];
  const float* W1     = (const float*)d_in[5];
  const float* b1     = (const float*)d_in[6];
  const float* W2     = (const float*)d_in[7];
  const float* b2     = (const float*)d_in[8];
  float* out = (float*)d_out;

  float* mix    = (float*)d_ws;        // NB*2
  float* stats  = mix + NB * 2;        // NB*2
  float* alphas = stats + NB * 2;      // NB*NS
  float* h      = alphas + NB * NS;    // NB*ND  (~1.6 MB total ws use)

  // h = tanh(x @ W1 + b1)
  gemm_bias<true><<<dim3(ND / 64, NB / 64), 256, 0, stream>>>(x, W1, b1, h, NB, ND, ND);
  // mix = softmax2(h @ W2 + b2)
  gate_mix<<<NB, 256, 0, stream>>>(h, W2, b2, mix);
  // alphas = softmax(scores)
  softmax_scores<<<NB, 256, 0, stream>>>(scores, alphas);
  // logits = x @ Wg + bg  -> d_out
  gemm_bias<false><<<dim3((NV + 63) / 64, NB / 64), 256, 0, stream>>>(x, Wg, bg, out, NB, NV, ND);
  // per-row max/sum
  row_max_sum<<<NB, 256, 0, stream>>>(out, stats);
  // out = softmax * mix0 (in place)
  finalize_gen<<<dim3((NV + 255) / 256, NB), 256, 0, stream>>>(out, stats, mix);
  // scatter copy distribution
  scatter_copy<<<NB, NS, 0, stream>>>(out, alphas, ctx, mix);
}

// Round 2
// 293.990 us; speedup vs baseline: 2.2083x; 2.2083x over previous
//
#include <hip/hip_runtime.h>
#include <hip/hip_bf16.h>
#include <math.h>

constexpr int NB = 256;    // batch
constexpr int NS = 512;    // source positions
constexpr int ND = 1024;   // hidden
constexpr int NV = 50257;  // vocab

typedef __attribute__((ext_vector_type(8))) short bf16x8;
typedef __attribute__((ext_vector_type(4))) short bf16x4;
typedef __attribute__((ext_vector_type(4))) float f32x4;

__device__ inline short f2bf(float f) {
  unsigned u = __builtin_bit_cast(unsigned, f);
  u = (u + 0x7FFFu + ((u >> 16) & 1u)) >> 16;   // RNE
  return (short)u;
}

// ---------------------------------------------------------------------------
// Logits GEMM: out[256, NV] = x[256,1024] @ Wg[1024,NV] + bg, bf16 MFMA.
// BM=256 (full M, so Wg is streamed exactly once), BN=64, BK=64, 256 threads.
// f32->bf16 conversion fused into LDS staging. XOR-swizzled LDS (G4).
// ---------------------------------------------------------------------------
__global__ __launch_bounds__(256, 3)
void gemm_logits(const float* __restrict__ x, const float* __restrict__ Wg,
                 const float* __restrict__ bg, float* __restrict__ out) {
  __shared__ __align__(16) short As[256 * 64];   // [m][k] bf16, swizzled, 32 KB
  __shared__ __align__(16) short Bs[64 * 64];    // [n][k] bf16, swizzled, 8 KB
  const int tid = threadIdx.x;
  const int lane = tid & 63, wave = tid >> 6;
  const int n0 = blockIdx.x * 64;

  f32x4 acc[4][4] = {};

  const int kq = tid >> 4;   // 0..15: k-quad for B staging
  const int nq = tid & 15;   // 0..15: n-quad for B staging

  for (int k0 = 0; k0 < ND; k0 += 64) {
    // ---- stage A: x tile 256x64, f32 -> bf16, row-major [m][k], swizzled ----
#pragma unroll
    for (int i = 0; i < 8; ++i) {
      int s = i * 256 + tid;
      int m = s >> 3, slot = s & 7;            // slot = 8-k chunk
      const float4* src = reinterpret_cast<const float4*>(x + m * ND + k0 + slot * 8);
      float4 f0 = src[0], f1 = src[1];
      bf16x8 v = { f2bf(f0.x), f2bf(f0.y), f2bf(f0.z), f2bf(f0.w),
                   f2bf(f1.x), f2bf(f1.y), f2bf(f1.z), f2bf(f1.w) };
      *reinterpret_cast<bf16x8*>(reinterpret_cast<char*>(As) +
                                 m * 128 + ((slot ^ (m & 7)) << 4)) = v;
    }
    // ---- stage B: Wg tile 64x64, f32 -> bf16, TRANSPOSED to [n][k], swizzled.
    // Scalar f32 loads (NV is odd -> rows not 16B aligned); 16 lanes x 4 dwords
    // consecutive = 256B contiguous per k-row. ----
    float vals[4][4];
#pragma unroll
    for (int kk = 0; kk < 4; ++kk) {
      const float* src = Wg + (k0 + kq * 4 + kk) * NV + n0 + nq * 4;
#pragma unroll
      for (int nn = 0; nn < 4; ++nn) {
        int col = n0 + nq * 4 + nn;
        vals[kk][nn] = (col < NV) ? src[nn] : 0.0f;
      }
    }
#pragma unroll
    for (int nn = 0; nn < 4; ++nn) {
      int n = nq * 4 + nn;
      bf16x4 q = { f2bf(vals[0][nn]), f2bf(vals[1][nn]),
                   f2bf(vals[2][nn]), f2bf(vals[3][nn]) };
      int byte = n * 128 + ((((kq >> 1) ^ (n & 7)) << 4) | ((kq & 1) << 3));
      *reinterpret_cast<bf16x4*>(reinterpret_cast<char*>(Bs) + byte) = q;
    }
    __syncthreads();
    // ---- compute: each wave owns rows [wave*64, wave*64+64), all 64 cols ----
    const int c16 = lane & 15;
#pragma unroll
    for (int kk = 0; kk < 2; ++kk) {
      int slot = kk * 4 + (lane >> 4);
      bf16x8 a[4], b[4];
#pragma unroll
      for (int mi = 0; mi < 4; ++mi) {
        int m = wave * 64 + mi * 16 + c16;
        a[mi] = *reinterpret_cast<const bf16x8*>(reinterpret_cast<const char*>(As) +
                                                 m * 128 + ((slot ^ (m & 7)) << 4));
      }
#pragma unroll
      for (int ni = 0; ni < 4; ++ni) {
        int n = ni * 16 + c16;
        b[ni] = *reinterpret_cast<const bf16x8*>(reinterpret_cast<const char*>(Bs) +
                                                 n * 128 + ((slot ^ (n & 7)) << 4));
      }
#pragma unroll
      for (int mi = 0; mi < 4; ++mi)
#pragma unroll
        for (int ni = 0; ni < 4; ++ni)
          acc[mi][ni] = __builtin_amdgcn_mfma_f32_16x16x32_bf16(a[mi], b[ni], acc[mi][ni], 0, 0, 0);
    }
    __syncthreads();
  }
  // ---- epilogue: C/D layout col=lane&15, row=(lane>>4)*4+reg ----
#pragma unroll
  for (int mi = 0; mi < 4; ++mi) {
#pragma unroll
    for (int ni = 0; ni < 4; ++ni) {
      int col = n0 + ni * 16 + (lane & 15);
      if (col < NV) {
        float bv = bg[col];
#pragma unroll
        for (int r = 0; r < 4; ++r) {
          int row = wave * 64 + mi * 16 + (lane >> 4) * 4 + r;
          out[row * NV + col] = acc[mi][ni][r] + bv;
        }
      }
    }
  }
}

// ---------------------------------------------------------------------------
// Tiled f32 GEMM for the small gate path: C = tanh(A @ Bm + bias)
// ---------------------------------------------------------------------------
template<bool TANH_ACT>
__global__ __launch_bounds__(256)
void gemm_bias(const float* __restrict__ A, const float* __restrict__ Bm,
               const float* __restrict__ bias, float* __restrict__ C,
               int M, int N, int K) {
  constexpr int BM = 64, BN = 64, BK = 16, PAD = 4;
  __shared__ float As[BK][BM + PAD];
  __shared__ float Bs[BK][BN + PAD];
  const int tid = threadIdx.x;
  const int tx = tid & 15;
  const int ty = tid >> 4;
  const int row0 = blockIdx.y * BM;
  const int col0 = blockIdx.x * BN;

  float acc[4][4] = {};

  for (int k0 = 0; k0 < K; k0 += BK) {
#pragma unroll
    for (int l = 0; l < 4; ++l) {
      int e = tid + l * 256;
      int r = e >> 4, c = e & 15;
      As[c][r] = A[(row0 + r) * K + k0 + c];
    }
#pragma unroll
    for (int l = 0; l < 4; ++l) {
      int e = tid + l * 256;
      int r = e >> 6, c = e & 63;
      int col = col0 + c;
      Bs[r][c] = (col < N) ? Bm[(k0 + r) * N + col] : 0.0f;
    }
    __syncthreads();
#pragma unroll
    for (int k = 0; k < BK; ++k) {
      float a[4], b[4];
#pragma unroll
      for (int i = 0; i < 4; ++i) a[i] = As[k][ty * 4 + i];
#pragma unroll
      for (int j = 0; j < 4; ++j) b[j] = Bs[k][tx * 4 + j];
#pragma unroll
      for (int i = 0; i < 4; ++i)
#pragma unroll
        for (int j = 0; j < 4; ++j)
          acc[i][j] += a[i] * b[j];
    }
    __syncthreads();
  }

#pragma unroll
  for (int i = 0; i < 4; ++i) {
    int row = row0 + ty * 4 + i;
#pragma unroll
    for (int j = 0; j < 4; ++j) {
      int col = col0 + tx * 4 + j;
      if (col < N) {
        float v = acc[i][j] + bias[col];
        if (TANH_ACT) v = tanhf(v);
        C[row * N + col] = v;
      }
    }
  }
}

// ---------------------------------------------------------------------------
// mix = softmax2(h @ W2 + b2), one block per row
// ---------------------------------------------------------------------------
__global__ __launch_bounds__(256)
void gate_mix(const float* __restrict__ h, const float* __restrict__ W2,
              const float* __restrict__ b2, float* __restrict__ mix) {
  const int row = blockIdx.x;
  const int tid = threadIdx.x;
  float g0 = 0.f, g1 = 0.f;
  for (int j = tid; j < ND; j += 256) {
    float hv = h[row * ND + j];
    g0 += hv * W2[j * 2 + 0];
    g1 += hv * W2[j * 2 + 1];
  }
  for (int o = 32; o > 0; o >>= 1) {
    g0 += __shfl_down(g0, o, 64);
    g1 += __shfl_down(g1, o, 64);
  }
  __shared__ float l0[4], l1[4];
  int wid = tid >> 6, lane = tid & 63;
  if (lane == 0) { l0[wid] = g0; l1[wid] = g1; }
  __syncthreads();
  if (tid == 0) {
    float a = l0[0] + l0[1] + l0[2] + l0[3] + b2[0];
    float c = l1[0] + l1[1] + l1[2] + l1[3] + b2[1];
    float m = fmaxf(a, c);
    float e0 = expf(a - m), e1 = expf(c - m);
    float inv = 1.f / (e0 + e1);
    mix[row * 2 + 0] = e0 * inv;
    mix[row * 2 + 1] = e1 * inv;
  }
}

// ---------------------------------------------------------------------------
// alphas = softmax(scores) rowwise
// ---------------------------------------------------------------------------
__global__ __launch_bounds__(256)
void softmax_scores(const float* __restrict__ scores, float* __restrict__ alphas) {
  const int row = blockIdx.x;
  const int tid = threadIdx.x;
  float v0 = scores[row * NS + tid];
  float v1 = scores[row * NS + tid + 256];
  float m = fmaxf(v0, v1);
  for (int o = 32; o > 0; o >>= 1) m = fmaxf(m, __shfl_down(m, o, 64));
  __shared__ float lm[4], ls[4];
  int wid = tid >> 6, lane = tid & 63;
  if (lane == 0) lm[wid] = m;
  __syncthreads();
  float mAll = fmaxf(fmaxf(lm[0], lm[1]), fmaxf(lm[2], lm[3]));
  float e0 = expf(v0 - mAll), e1 = expf(v1 - mAll);
  float s = e0 + e1;
  for (int o = 32; o > 0; o >>= 1) s += __shfl_down(s, o, 64);
  if (lane == 0) ls[wid] = s;
  __syncthreads();
  float inv = 1.f / (ls[0] + ls[1] + ls[2] + ls[3]);
  alphas[row * NS + tid] = e0 * inv;
  alphas[row * NS + tid + 256] = e1 * inv;
}

// ---------------------------------------------------------------------------
// Per-row online max/sum over V logits, one 1024-thread block per row.
// ---------------------------------------------------------------------------
__global__ __launch_bounds__(1024)
void row_max_sum(const float* __restrict__ logits, float* __restrict__ stats) {
  const int row = blockIdx.x;
  const int tid = threadIdx.x;
  float m = -INFINITY, s = 0.f;
  for (int c = tid; c < NV; c += 1024) {
    float x = logits[row * NV + c];
    if (x <= m) {
      s += expf(x - m);
    } else {
      s = s * expf(m - x) + 1.0f;
      m = x;
    }
  }
  for (int o = 32; o > 0; o >>= 1) {
    float m2 = __shfl_down(m, o, 64);
    float s2 = __shfl_down(s, o, 64);
    float mn = fmaxf(m, m2);
    s = s * expf(m - mn) + s2 * expf(m2 - mn);
    m = mn;
  }
  __shared__ float lm[16], ls[16];
  int wid = tid >> 6, lane = tid & 63;
  if (lane == 0) { lm[wid] = m; ls[wid] = s; }
  __syncthreads();
  if (tid == 0) {
    float M = lm[0], Sv = ls[0];
    for (int w = 1; w < 16; ++w) {
      float mn = fmaxf(M, lm[w]);
      Sv = Sv * expf(M - mn) + ls[w] * expf(lm[w] - mn);
      M = mn;
    }
    stats[row * 2 + 0] = M;
    stats[row * 2 + 1] = Sv;
  }
}

// ---------------------------------------------------------------------------
// out = exp(logit - m)/s * mix0   (in-place on d_out)
// ---------------------------------------------------------------------------
__global__ __launch_bounds__(256)
void finalize_gen(float* __restrict__ out, const float* __restrict__ stats,
                  const float* __restrict__ mix) {
  const int row = blockIdx.y;
  const int col = blockIdx.x * 256 + threadIdx.x;
  if (col < NV) {
    float m = stats[row * 2 + 0], s = stats[row * 2 + 1];
    float g = mix[row * 2 + 0];
    float x = out[row * NV + col];
    out[row * NV + col] = expf(x - m) * (g / s);
  }
}

// ---------------------------------------------------------------------------
// out[row, ctx_ids[row,s]] += alphas[row,s] * mix1[row]
// ---------------------------------------------------------------------------
__global__ __launch_bounds__(512)
void scatter_copy(float* __restrict__ out, const float* __restrict__ alphas,
                  const int* __restrict__ ids, const float* __restrict__ mix) {
  const int row = blockIdx.x;
  const int t = threadIdx.x;
  float a = alphas[row * NS + t] * mix[row * 2 + 1];
  atomicAdd(&out[row * NV + ids[row * NS + t]], a);
}

extern "C" void kernel_launch(void* const* d_in, const int* in_sizes, int n_in,
                              void* d_out, int out_size, void* d_ws, size_t ws_size,
                              hipStream_t stream) {
  const float* x      = (const float*)d_in[0];
  const float* scores = (const float*)d_in[1];
  const int*   ctx    = (const int*)d_in[2];
  const float* Wg     = (const float*)d_in[3];
  const float* bg     = (const float*)d_in[4];
  const float* W1     = (const float*)d_in[5];
  const float* b1     = (const float*)d_in[6];
  const float* W2     = (const float*)d_in[7];
  const float* b2     = (const float*)d_in[8];
  float* out = (float*)d_out;

  float* mix    = (float*)d_ws;        // NB*2
  float* stats  = mix + NB * 2;        // NB*2
  float* alphas = stats + NB * 2;      // NB*NS
  float* h      = alphas + NB * NS;    // NB*ND

  // h = tanh(x @ W1 + b1)   (small, stays f32)
  gemm_bias<true><<<dim3(ND / 64, NB / 64), 256, 0, stream>>>(x, W1, b1, h, NB, ND, ND);
  // mix = softmax2(h @ W2 + b2)
  gate_mix<<<NB, 256, 0, stream>>>(h, W2, b2, mix);
  // alphas = softmax(scores)
  softmax_scores<<<NB, 256, 0, stream>>>(scores, alphas);
  // logits = x @ Wg + bg  -> d_out   (bf16 MFMA, Wg streamed once)
  gemm_logits<<<(NV + 63) / 64, 256, 0, stream>>>(x, Wg, bg, out);
  // per-row max/sum
  row_max_sum<<<NB, 1024, 0, stream>>>(out, stats);
  // out = softmax * mix0 (in place)
  finalize_gen<<<dim3((NV + 255) / 256, NB), 256, 0, stream>>>(out, stats, mix);
  // scatter copy distribution
  scatter_copy<<<NB, NS, 0, stream>>>(out, alphas, ctx, mix);
}